// Round 1
// baseline (385.658 us; speedup 1.0000x reference)
//
#include <hip/hip_runtime.h>

#define NN 50000
#define NE 1000000

// ---------------- edge MLP + degree count ----------------
// w_e[e] = relu(ea[e]@w1 + b1) @ w2 + b2 ; deg[dst[e]] += 1
__global__ void edge_mlp_deg(const float* __restrict__ ea,
                             const int* __restrict__ dst,
                             const float* __restrict__ w1,
                             const float* __restrict__ b1,
                             const float* __restrict__ w2,
                             const float* __restrict__ b2,
                             float* __restrict__ we,
                             float* __restrict__ deg) {
    __shared__ float sw1[192];
    __shared__ float sb1[64];
    __shared__ float sw2[64];
    int t = threadIdx.x;
    if (t < 192) sw1[t] = w1[t];
    if (t < 64) { sb1[t] = b1[t]; sw2[t] = w2[t]; }
    __syncthreads();
    int e = blockIdx.x * blockDim.x + t;
    if (e >= NE) return;
    float a0 = ea[3 * e + 0];
    float a1 = ea[3 * e + 1];
    float a2 = ea[3 * e + 2];
    float acc = b2[0];
#pragma unroll
    for (int j = 0; j < 64; ++j) {
        float hj = fmaf(a0, sw1[j], fmaf(a1, sw1[64 + j], fmaf(a2, sw1[128 + j], sb1[j])));
        acc = fmaf(fmaxf(hj, 0.f), sw2[j], acc);
    }
    we[e] = acc;
    atomicAdd(&deg[dst[e]], 1.0f);
}

// ---------------- node init: inv_deg, zero agg, h = x[:,2] ----------------
__global__ void node_init(const float* __restrict__ x,
                          float* __restrict__ deg_io,   // in: deg, out: inv_deg
                          float* __restrict__ agg,
                          float* __restrict__ h) {
    int i = blockIdx.x * blockDim.x + threadIdx.x;
    if (i >= NN) return;
    float d = deg_io[i];
    deg_io[i] = (d > 0.f) ? (1.0f / d) : 0.f;
    agg[i] = 0.f;
    h[i] = x[5 * i + 2];
}

// ---------------- fold inv_deg into per-edge coefficient ----------------
__global__ void edge_coeff(const int* __restrict__ dst,
                           const float* __restrict__ inv_deg,
                           float* __restrict__ we) {
    int e = blockIdx.x * blockDim.x + threadIdx.x;
    if (e >= NE) return;
    we[e] *= inv_deg[dst[e]];
}

// ---------------- per-round scatter: agg[dst] += h[src]*c_e ----------------
__global__ void scatter_edges(const int* __restrict__ src,
                              const int* __restrict__ dst,
                              const float* __restrict__ ce,
                              const float* __restrict__ h,
                              float* __restrict__ agg) {
    int e = blockIdx.x * blockDim.x + threadIdx.x;
    if (e >= NE) return;
    atomicAdd(&agg[dst[e]], h[src[e]] * ce[e]);
}

// ---------------- per-round node update (re-zeroes agg for next round) ----
__global__ void node_update(float* __restrict__ h,
                            float* __restrict__ agg,
                            const float* __restrict__ root,
                            const float* __restrict__ bias) {
    int i = blockIdx.x * blockDim.x + threadIdx.x;
    if (i >= NN) return;
    float a = agg[i];
    agg[i] = 0.f;
    h[i] = fmaxf(fmaf(h[i], root[0], a + bias[0]), 0.f);
}

extern "C" void kernel_launch(void* const* d_in, const int* in_sizes, int n_in,
                              void* d_out, int out_size, void* d_ws, size_t ws_size,
                              hipStream_t stream) {
    const float* x    = (const float*)d_in[0];
    const int*   ei   = (const int*)d_in[1];
    const float* ea   = (const float*)d_in[2];
    const float* w1   = (const float*)d_in[3];
    const float* b1   = (const float*)d_in[4];
    const float* w2   = (const float*)d_in[5];
    const float* b2   = (const float*)d_in[6];
    const float* root = (const float*)d_in[7];
    const float* bias = (const float*)d_in[8];

    const int* src = ei;            // edge_index[0]
    const int* dst = ei + NE;       // edge_index[1]

    float* h   = (float*)d_out;     // N floats, lives in d_out the whole time
    float* ce  = (float*)d_ws;                  // E floats (w_e then c_e in place)
    float* deg = ce + NE;                       // N floats (deg then inv_deg in place)
    float* agg = deg + NN;                      // N floats

    const int BLK = 256;
    const int gE = (NE + BLK - 1) / BLK;
    const int gN = (NN + BLK - 1) / BLK;

    hipMemsetAsync(deg, 0, NN * sizeof(float), stream);

    edge_mlp_deg<<<gE, BLK, 0, stream>>>(ea, dst, w1, b1, w2, b2, ce, deg);
    node_init<<<gN, BLK, 0, stream>>>(x, deg, agg, h);
    edge_coeff<<<gE, BLK, 0, stream>>>(dst, deg, ce);

    for (int r = 0; r < 4; ++r) {
        scatter_edges<<<gE, BLK, 0, stream>>>(src, dst, ce, h, agg);
        node_update<<<gN, BLK, 0, stream>>>(h, agg, root, bias);
    }
}

// Round 2
// 372.233 us; speedup vs baseline: 1.0361x; 1.0361x over previous
//
#include <hip/hip_runtime.h>

#define NN 50000
#define NE 1000000

// ================= fast path (CSR gather) =================

__global__ void count_kernel(const int* __restrict__ dst, int* __restrict__ cnt) {
    int e = blockIdx.x * blockDim.x + threadIdx.x;
    if (e < NE) atomicAdd(&cnt[dst[e]], 1);
}

// single block, 1024 threads: exclusive scan of cnt -> row & cursor, plus inv_deg
__global__ void scan_kernel(const int* __restrict__ cnt,
                            int* __restrict__ row,
                            int* __restrict__ cursor,
                            float* __restrict__ invdeg) {
    __shared__ int part[1024];
    const int t = threadIdx.x;
    const int CH = (NN + 1023) / 1024;   // 49
    int lo = t * CH;
    int hi = lo + CH; if (hi > NN) hi = NN;
    int s = 0;
    for (int i = lo; i < hi; ++i) {
        int c = cnt[i];
        s += c;
        invdeg[i] = (c > 0) ? (1.0f / (float)c) : 0.0f;
    }
    part[t] = s;
    __syncthreads();
    // Hillis-Steele inclusive scan over 1024 partials
    for (int off = 1; off < 1024; off <<= 1) {
        int v = part[t];
        int add = (t >= off) ? part[t - off] : 0;
        __syncthreads();
        part[t] = v + add;
        __syncthreads();
    }
    int run = (t > 0) ? part[t - 1] : 0;
    for (int i = lo; i < hi; ++i) {
        row[i] = run;
        cursor[i] = run;
        run += cnt[i];
    }
    if (t == 1023) row[NN] = NE;
}

__global__ void node_init(const float* __restrict__ x, float* __restrict__ h) {
    int i = blockIdx.x * blockDim.x + threadIdx.x;
    if (i < NN) h[i] = x[5 * i + 2];
}

// edge MLP + fold inv_deg + counting-sort placement into (src, ce) pairs
__global__ void place_kernel(const float* __restrict__ ea,
                             const int* __restrict__ src,
                             const int* __restrict__ dst,
                             const float* __restrict__ w1,
                             const float* __restrict__ b1,
                             const float* __restrict__ w2,
                             const float* __restrict__ b2,
                             const float* __restrict__ invdeg,
                             int* __restrict__ cursor,
                             uint2* __restrict__ es) {
    __shared__ float sw1[192];
    __shared__ float sb1[64];
    __shared__ float sw2[64];
    int t = threadIdx.x;
    if (t < 192) sw1[t] = w1[t];
    if (t < 64) { sb1[t] = b1[t]; sw2[t] = w2[t]; }
    __syncthreads();
    int e = blockIdx.x * blockDim.x + t;
    if (e >= NE) return;
    float a0 = ea[3 * e + 0];
    float a1 = ea[3 * e + 1];
    float a2 = ea[3 * e + 2];
    float acc = b2[0];
#pragma unroll
    for (int j = 0; j < 64; ++j) {
        float hj = fmaf(a0, sw1[j], fmaf(a1, sw1[64 + j], fmaf(a2, sw1[128 + j], sb1[j])));
        acc = fmaf(fmaxf(hj, 0.f), sw2[j], acc);
    }
    int d = dst[e];
    float ce = acc * invdeg[d];
    int p = atomicAdd(&cursor[d], 1);
    es[p] = make_uint2((unsigned)src[e], __float_as_uint(ce));
}

// one thread per node: agg gather + update, no atomics
__global__ void round_kernel(const int* __restrict__ row,
                             const uint2* __restrict__ es,
                             const float* __restrict__ hold,
                             float* __restrict__ hnew,
                             const float* __restrict__ root,
                             const float* __restrict__ bias) {
    int i = blockIdx.x * blockDim.x + threadIdx.x;
    if (i >= NN) return;
    int b = row[i], e2 = row[i + 1];
    float acc = 0.f;
    for (int p = b; p < e2; ++p) {
        uint2 v = es[p];
        acc = fmaf(hold[v.x], __uint_as_float(v.y), acc);
    }
    hnew[i] = fmaxf(fmaf(hold[i], root[0], acc + bias[0]), 0.f);
}

// ================= fallback path (R1 scatter, needs only ~4.4 MB ws) =================

__global__ void edge_mlp_deg(const float* __restrict__ ea,
                             const int* __restrict__ dst,
                             const float* __restrict__ w1,
                             const float* __restrict__ b1,
                             const float* __restrict__ w2,
                             const float* __restrict__ b2,
                             float* __restrict__ we,
                             float* __restrict__ deg) {
    __shared__ float sw1[192];
    __shared__ float sb1[64];
    __shared__ float sw2[64];
    int t = threadIdx.x;
    if (t < 192) sw1[t] = w1[t];
    if (t < 64) { sb1[t] = b1[t]; sw2[t] = w2[t]; }
    __syncthreads();
    int e = blockIdx.x * blockDim.x + t;
    if (e >= NE) return;
    float a0 = ea[3 * e + 0];
    float a1 = ea[3 * e + 1];
    float a2 = ea[3 * e + 2];
    float acc = b2[0];
#pragma unroll
    for (int j = 0; j < 64; ++j) {
        float hj = fmaf(a0, sw1[j], fmaf(a1, sw1[64 + j], fmaf(a2, sw1[128 + j], sb1[j])));
        acc = fmaf(fmaxf(hj, 0.f), sw2[j], acc);
    }
    we[e] = acc;
    atomicAdd(&deg[dst[e]], 1.0f);
}

__global__ void node_init_fb(const float* __restrict__ x,
                             float* __restrict__ deg_io,
                             float* __restrict__ agg,
                             float* __restrict__ h) {
    int i = blockIdx.x * blockDim.x + threadIdx.x;
    if (i >= NN) return;
    float d = deg_io[i];
    deg_io[i] = (d > 0.f) ? (1.0f / d) : 0.f;
    agg[i] = 0.f;
    h[i] = x[5 * i + 2];
}

__global__ void edge_coeff(const int* __restrict__ dst,
                           const float* __restrict__ inv_deg,
                           float* __restrict__ we) {
    int e = blockIdx.x * blockDim.x + threadIdx.x;
    if (e >= NE) return;
    we[e] *= inv_deg[dst[e]];
}

__global__ void scatter_edges(const int* __restrict__ src,
                              const int* __restrict__ dst,
                              const float* __restrict__ ce,
                              const float* __restrict__ h,
                              float* __restrict__ agg) {
    int e = blockIdx.x * blockDim.x + threadIdx.x;
    if (e >= NE) return;
    atomicAdd(&agg[dst[e]], h[src[e]] * ce[e]);
}

__global__ void node_update(float* __restrict__ h,
                            float* __restrict__ agg,
                            const float* __restrict__ root,
                            const float* __restrict__ bias) {
    int i = blockIdx.x * blockDim.x + threadIdx.x;
    if (i >= NN) return;
    float a = agg[i];
    agg[i] = 0.f;
    h[i] = fmaxf(fmaf(h[i], root[0], a + bias[0]), 0.f);
}

// ================= launch =================

extern "C" void kernel_launch(void* const* d_in, const int* in_sizes, int n_in,
                              void* d_out, int out_size, void* d_ws, size_t ws_size,
                              hipStream_t stream) {
    const float* x    = (const float*)d_in[0];
    const int*   ei   = (const int*)d_in[1];
    const float* ea   = (const float*)d_in[2];
    const float* w1   = (const float*)d_in[3];
    const float* b1   = (const float*)d_in[4];
    const float* w2   = (const float*)d_in[5];
    const float* b2   = (const float*)d_in[6];
    const float* root = (const float*)d_in[7];
    const float* bias = (const float*)d_in[8];

    const int* src = ei;
    const int* dst = ei + NE;

    float* h = (float*)d_out;

    const int BLK = 256;
    const int gE = (NE + BLK - 1) / BLK;
    const int gN = (NN + BLK - 1) / BLK;

    // fast-path workspace layout (8-byte aligned base assumed)
    const size_t need = (size_t)NE * 8        // es pairs
                      + (size_t)(NN + 1) * 4  // row
                      + (size_t)NN * 4        // cursor
                      + (size_t)NN * 4        // cnt
                      + (size_t)NN * 4        // invdeg
                      + (size_t)NN * 4;       // hB

    if (ws_size >= need) {
        uint2* es     = (uint2*)d_ws;
        int*   row    = (int*)(es + NE);
        int*   cursor = row + (NN + 1);
        int*   cnt    = cursor + NN;
        float* invdeg = (float*)(cnt + NN);
        float* hB     = invdeg + NN;

        hipMemsetAsync(cnt, 0, NN * sizeof(int), stream);
        count_kernel<<<gE, BLK, 0, stream>>>(dst, cnt);
        scan_kernel<<<1, 1024, 0, stream>>>(cnt, row, cursor, invdeg);
        node_init<<<gN, BLK, 0, stream>>>(x, h);
        place_kernel<<<gE, BLK, 0, stream>>>(ea, src, dst, w1, b1, w2, b2,
                                             invdeg, cursor, es);
        // rounds: h(d_out) -> hB -> h -> hB -> h  (final lands in d_out)
        round_kernel<<<gN, BLK, 0, stream>>>(row, es, h,  hB, root, bias);
        round_kernel<<<gN, BLK, 0, stream>>>(row, es, hB, h,  root, bias);
        round_kernel<<<gN, BLK, 0, stream>>>(row, es, h,  hB, root, bias);
        round_kernel<<<gN, BLK, 0, stream>>>(row, es, hB, h,  root, bias);
    } else {
        // fallback: R1 scatter path (~4.4 MB ws)
        float* ce  = (float*)d_ws;
        float* deg = ce + NE;
        float* agg = deg + NN;

        hipMemsetAsync(deg, 0, NN * sizeof(float), stream);
        edge_mlp_deg<<<gE, BLK, 0, stream>>>(ea, dst, w1, b1, w2, b2, ce, deg);
        node_init_fb<<<gN, BLK, 0, stream>>>(x, deg, agg, h);
        edge_coeff<<<gE, BLK, 0, stream>>>(dst, deg, ce);
        for (int r = 0; r < 4; ++r) {
            scatter_edges<<<gE, BLK, 0, stream>>>(src, dst, ce, h, agg);
            node_update<<<gN, BLK, 0, stream>>>(h, agg, root, bias);
        }
    }
}

// Round 3
// 215.840 us; speedup vs baseline: 1.7868x; 1.7246x over previous
//
#include <hip/hip_runtime.h>

#define NN 50000
#define NE 1000000
#define NB 196   // ceil(NN/256)

// ---------------- count degrees ----------------
__global__ void count_kernel(const int* __restrict__ dst, int* __restrict__ cnt) {
    int e = blockIdx.x * blockDim.x + threadIdx.x;
    if (e < NE) atomicAdd(&cnt[dst[e]], 1);
}

// ---------------- scan stage 1: per-block sums + invdeg ----------------
__global__ void scan_stage1(const int* __restrict__ cnt,
                            int* __restrict__ blocksum,
                            float* __restrict__ invdeg) {
    __shared__ int sdata[256];
    int t = threadIdx.x;
    int i = blockIdx.x * 256 + t;
    int c = (i < NN) ? cnt[i] : 0;
    if (i < NN) invdeg[i] = (c > 0) ? (1.0f / (float)c) : 0.0f;
    sdata[t] = c;
    __syncthreads();
    for (int s = 128; s > 0; s >>= 1) {
        if (t < s) sdata[t] += sdata[t + s];
        __syncthreads();
    }
    if (t == 0) blocksum[blockIdx.x] = sdata[0];
}

// ---------------- scan stage 2: exclusive scan of 196 block sums ----------
__global__ void scan_stage2(const int* __restrict__ blocksum,
                            int* __restrict__ blockoff) {
    __shared__ int part[256];
    int t = threadIdx.x;
    int v = (t < NB) ? blocksum[t] : 0;
    part[t] = v;
    __syncthreads();
    for (int off = 1; off < 256; off <<= 1) {
        int x = part[t];
        int add = (t >= off) ? part[t - off] : 0;
        __syncthreads();
        part[t] = x + add;
        __syncthreads();
    }
    if (t < NB) blockoff[t] = part[t] - v;   // exclusive
}

// ---------------- scan stage 3: local scan + offset -> row/cursor; h init --
__global__ void scan_stage3(const int* __restrict__ cnt,
                            const int* __restrict__ blockoff,
                            const float* __restrict__ x,
                            int* __restrict__ row,
                            int* __restrict__ cursor,
                            float* __restrict__ h) {
    __shared__ int part[256];
    int t = threadIdx.x;
    int i = blockIdx.x * 256 + t;
    int c = (i < NN) ? cnt[i] : 0;
    part[t] = c;
    __syncthreads();
    for (int off = 1; off < 256; off <<= 1) {
        int xv = part[t];
        int add = (t >= off) ? part[t - off] : 0;
        __syncthreads();
        part[t] = xv + add;
        __syncthreads();
    }
    int excl = part[t] - c + blockoff[blockIdx.x];
    if (i < NN) {
        row[i] = excl;
        cursor[i] = excl;
        h[i] = x[5 * i + 2];
    }
    if (i == NN - 1) row[NN] = excl + c;   // == NE
}

// ---------------- edge MLP + fold inv_deg + counting-sort placement -------
__global__ void place_kernel(const float* __restrict__ ea,
                             const int* __restrict__ src,
                             const int* __restrict__ dst,
                             const float* __restrict__ w1,
                             const float* __restrict__ b1,
                             const float* __restrict__ w2,
                             const float* __restrict__ b2,
                             const float* __restrict__ invdeg,
                             int* __restrict__ cursor,
                             uint2* __restrict__ es) {
    __shared__ float sw1[192];
    __shared__ float sb1[64];
    __shared__ float sw2[64];
    int t = threadIdx.x;
    if (t < 192) sw1[t] = w1[t];
    if (t < 64) { sb1[t] = b1[t]; sw2[t] = w2[t]; }
    __syncthreads();
    int e = blockIdx.x * blockDim.x + t;
    if (e >= NE) return;
    float a0 = ea[3 * e + 0];
    float a1 = ea[3 * e + 1];
    float a2 = ea[3 * e + 2];
    float acc = b2[0];
#pragma unroll
    for (int j = 0; j < 64; ++j) {
        float hj = fmaf(a0, sw1[j], fmaf(a1, sw1[64 + j], fmaf(a2, sw1[128 + j], sb1[j])));
        acc = fmaf(fmaxf(hj, 0.f), sw2[j], acc);
    }
    int d = dst[e];
    float ce = acc * invdeg[d];
    int p = atomicAdd(&cursor[d], 1);
    es[p] = make_uint2((unsigned)src[e], __float_as_uint(ce));
}

// ---------------- round: 16 lanes per node, shuffle reduce ----------------
__global__ void round_kernel(const int* __restrict__ row,
                             const uint2* __restrict__ es,
                             const float* __restrict__ hold,
                             float* __restrict__ hnew,
                             const float* __restrict__ root,
                             const float* __restrict__ bias) {
    int gt = blockIdx.x * blockDim.x + threadIdx.x;
    int i = gt >> 4;
    int l = gt & 15;
    if (i >= NN) return;
    int b = row[i], e2 = row[i + 1];
    float acc = 0.f;
    for (int p = b + l; p < e2; p += 16) {
        uint2 v = es[p];
        acc = fmaf(hold[v.x], __uint_as_float(v.y), acc);
    }
    acc += __shfl_xor(acc, 1, 16);
    acc += __shfl_xor(acc, 2, 16);
    acc += __shfl_xor(acc, 4, 16);
    acc += __shfl_xor(acc, 8, 16);
    if (l == 0) hnew[i] = fmaxf(fmaf(hold[i], root[0], acc + bias[0]), 0.f);
}

// ================= launch =================

extern "C" void kernel_launch(void* const* d_in, const int* in_sizes, int n_in,
                              void* d_out, int out_size, void* d_ws, size_t ws_size,
                              hipStream_t stream) {
    const float* x    = (const float*)d_in[0];
    const int*   ei   = (const int*)d_in[1];
    const float* ea   = (const float*)d_in[2];
    const float* w1   = (const float*)d_in[3];
    const float* b1   = (const float*)d_in[4];
    const float* w2   = (const float*)d_in[5];
    const float* b2   = (const float*)d_in[6];
    const float* root = (const float*)d_in[7];
    const float* bias = (const float*)d_in[8];

    const int* src = ei;
    const int* dst = ei + NE;

    float* h = (float*)d_out;

    const int BLK = 256;
    const int gE = (NE + BLK - 1) / BLK;
    const int gN = NB;                       // node-grid (196)
    const int gR = (NN * 16 + BLK - 1) / BLK; // 3125 blocks, 16 lanes/node

    // workspace layout
    uint2* es       = (uint2*)d_ws;          // NE * 8B
    int*   row      = (int*)(es + NE);       // NN+1
    int*   cursor   = row + (NN + 1);        // NN
    int*   cnt      = cursor + NN;           // NN
    float* invdeg   = (float*)(cnt + NN);    // NN
    float* hB       = invdeg + NN;           // NN
    int*   blocksum = (int*)(hB + NN);       // NB
    int*   blockoff = blocksum + NB;         // NB

    hipMemsetAsync(cnt, 0, NN * sizeof(int), stream);
    count_kernel<<<gE, BLK, 0, stream>>>(dst, cnt);
    scan_stage1<<<gN, BLK, 0, stream>>>(cnt, blocksum, invdeg);
    scan_stage2<<<1, 256, 0, stream>>>(blocksum, blockoff);
    scan_stage3<<<gN, BLK, 0, stream>>>(cnt, blockoff, x, row, cursor, h);
    place_kernel<<<gE, BLK, 0, stream>>>(ea, src, dst, w1, b1, w2, b2,
                                         invdeg, cursor, es);
    // rounds: h(d_out) -> hB -> h -> hB -> h (final lands in d_out)
    round_kernel<<<gR, BLK, 0, stream>>>(row, es, h,  hB, root, bias);
    round_kernel<<<gR, BLK, 0, stream>>>(row, es, hB, h,  root, bias);
    round_kernel<<<gR, BLK, 0, stream>>>(row, es, h,  hB, root, bias);
    round_kernel<<<gR, BLK, 0, stream>>>(row, es, hB, h,  root, bias);
}

// Round 4
// 175.759 us; speedup vs baseline: 2.1942x; 1.2280x over previous
//
#include <hip/hip_runtime.h>

#define NN 50000
#define NE 1000000
#define NBK 196          // buckets of 256 nodes: ceil(50000/256)
#define EPB 4096         // edges per block in count/place (256 thr x 16)
#define CPB 245          // ceil(NE/EPB)
#define RK 6             // round chunks per bucket

// ---------------- bucket histogram (196 cells) ----------------
__global__ void bucket_count(const int* __restrict__ dst, int* __restrict__ bcnt) {
    __shared__ int hist[NBK];
    int t = threadIdx.x;
    if (t < NBK) hist[t] = 0;
    __syncthreads();
#pragma unroll
    for (int j = 0; j < 16; ++j) {
        int e = blockIdx.x * EPB + j * 256 + t;
        if (e < NE) atomicAdd(&hist[dst[e] >> 8], 1);
    }
    __syncthreads();
    if (t < NBK && hist[t]) atomicAdd(&bcnt[t], hist[t]);
}

// ---------------- scan 196 bucket counts (1 block) ----------------
__global__ void bucket_scan(const int* __restrict__ bcnt,
                            int* __restrict__ base,
                            int* __restrict__ cursor) {
    __shared__ int part[256];
    int t = threadIdx.x;
    int v = (t < NBK) ? bcnt[t] : 0;
    part[t] = v;
    __syncthreads();
    for (int off = 1; off < 256; off <<= 1) {
        int x = part[t];
        int add = (t >= off) ? part[t - off] : 0;
        __syncthreads();
        part[t] = x + add;
        __syncthreads();
    }
    if (t < NBK) {
        int excl = part[t] - v;
        base[t] = excl;
        cursor[t] = excl;
    }
    if (t == NBK - 1) base[NBK] = part[t];   // == NE
}

// ---------------- h0 = x[:,2] ----------------
__global__ void h_init(const float* __restrict__ x, float* __restrict__ h) {
    int i = blockIdx.x * blockDim.x + threadIdx.x;
    if (i < NN) h[i] = x[5 * i + 2];
}

// ---------------- MLP + bucket-scatter with block-local ranks ----------------
__global__ void place_kernel(const float* __restrict__ ea,
                             const int* __restrict__ src,
                             const int* __restrict__ dst,
                             const float* __restrict__ w1,
                             const float* __restrict__ b1,
                             const float* __restrict__ w2,
                             const float* __restrict__ b2,
                             int* __restrict__ cursor,
                             uint2* __restrict__ es) {
    __shared__ float sw1[192];
    __shared__ float sb1[64];
    __shared__ float sw2[64];
    __shared__ float sce[EPB];
    __shared__ int hist[NBK];
    __shared__ int hbase[NBK];
    int t = threadIdx.x;
    if (t < 192) sw1[t] = w1[t];
    if (t < 64) { sb1[t] = b1[t]; sw2[t] = w2[t]; }
    if (t < NBK) hist[t] = 0;
    __syncthreads();

    int r[16];
#pragma unroll
    for (int j = 0; j < 16; ++j) {
        int e = blockIdx.x * EPB + j * 256 + t;
        if (e < NE) {
            float a0 = ea[3 * e + 0];
            float a1 = ea[3 * e + 1];
            float a2 = ea[3 * e + 2];
            float acc = b2[0];
#pragma unroll
            for (int k = 0; k < 64; ++k) {
                float hj = fmaf(a0, sw1[k], fmaf(a1, sw1[64 + k], fmaf(a2, sw1[128 + k], sb1[k])));
                acc = fmaf(fmaxf(hj, 0.f), sw2[k], acc);
            }
            sce[j * 256 + t] = acc;
            r[j] = atomicAdd(&hist[dst[e] >> 8], 1);
        }
    }
    __syncthreads();
    if (t < NBK && hist[t]) hbase[t] = atomicAdd(&cursor[t], hist[t]);
    __syncthreads();
#pragma unroll
    for (int j = 0; j < 16; ++j) {
        int e = blockIdx.x * EPB + j * 256 + t;
        if (e < NE) {
            int d = dst[e];
            int b = d >> 8;
            int pos = hbase[b] + r[j];
            unsigned pack = (unsigned)src[e] | ((unsigned)(d & 255) << 17);
            es[pos] = make_uint2(pack, __float_as_uint(sce[j * 256 + t]));
        }
    }
}

// ---------------- round 1 fused with degree count ----------------
__global__ void round1_deg(const int* __restrict__ base,
                           const uint2* __restrict__ es,
                           const float* __restrict__ hold,
                           float* __restrict__ agg,
                           int* __restrict__ deg) {
    __shared__ float lagg[256];
    __shared__ int ldeg[256];
    int t = threadIdx.x;
    int b = blockIdx.x / RK, c = blockIdx.x % RK;
    lagg[t] = 0.f;
    ldeg[t] = 0;
    __syncthreads();
    int s0 = base[b], s1 = base[b + 1];
    for (int p = s0 + c * 256 + t; p < s1; p += RK * 256) {
        uint2 v = es[p];
        int sidx = v.x & 0x1FFFF;
        int dl = (v.x >> 17) & 255;
        atomicAdd(&lagg[dl], hold[sidx] * __uint_as_float(v.y));
        atomicAdd(&ldeg[dl], 1);
    }
    __syncthreads();
    int node = b * 256 + t;
    if (node < NN) {
        float v = lagg[t];
        if (v != 0.f) atomicAdd(&agg[node], v);
        int d = ldeg[t];
        if (d) atomicAdd(&deg[node], d);
    }
}

// ---------------- rounds 2..4 ----------------
__global__ void round_kernel(const int* __restrict__ base,
                             const uint2* __restrict__ es,
                             const float* __restrict__ hold,
                             float* __restrict__ agg) {
    __shared__ float lagg[256];
    int t = threadIdx.x;
    int b = blockIdx.x / RK, c = blockIdx.x % RK;
    lagg[t] = 0.f;
    __syncthreads();
    int s0 = base[b], s1 = base[b + 1];
    for (int p = s0 + c * 256 + t; p < s1; p += RK * 256) {
        uint2 v = es[p];
        int sidx = v.x & 0x1FFFF;
        int dl = (v.x >> 17) & 255;
        atomicAdd(&lagg[dl], hold[sidx] * __uint_as_float(v.y));
    }
    __syncthreads();
    int node = b * 256 + t;
    if (node < NN) {
        float v = lagg[t];
        if (v != 0.f) atomicAdd(&agg[node], v);
    }
}

// ---------------- update 1: derive invdeg, apply update, re-zero agg -------
__global__ void update1(const int* __restrict__ deg,
                        float* __restrict__ invdeg,
                        float* __restrict__ agg,
                        const float* __restrict__ hold,
                        float* __restrict__ hnew,
                        const float* __restrict__ root,
                        const float* __restrict__ bias) {
    int i = blockIdx.x * blockDim.x + threadIdx.x;
    if (i >= NN) return;
    int d = deg[i];
    float inv = (d > 0) ? (1.0f / (float)d) : 0.f;
    invdeg[i] = inv;
    float a = agg[i];
    agg[i] = 0.f;
    hnew[i] = fmaxf(fmaf(hold[i], root[0], fmaf(a, inv, bias[0])), 0.f);
}

// ---------------- updates 2..4 ----------------
__global__ void update_kernel(const float* __restrict__ invdeg,
                              float* __restrict__ agg,
                              const float* __restrict__ hold,
                              float* __restrict__ hnew,
                              const float* __restrict__ root,
                              const float* __restrict__ bias) {
    int i = blockIdx.x * blockDim.x + threadIdx.x;
    if (i >= NN) return;
    float a = agg[i];
    agg[i] = 0.f;
    hnew[i] = fmaxf(fmaf(hold[i], root[0], fmaf(a, invdeg[i], bias[0])), 0.f);
}

// ================= launch =================

extern "C" void kernel_launch(void* const* d_in, const int* in_sizes, int n_in,
                              void* d_out, int out_size, void* d_ws, size_t ws_size,
                              hipStream_t stream) {
    const float* x    = (const float*)d_in[0];
    const int*   ei   = (const int*)d_in[1];
    const float* ea   = (const float*)d_in[2];
    const float* w1   = (const float*)d_in[3];
    const float* b1   = (const float*)d_in[4];
    const float* w2   = (const float*)d_in[5];
    const float* b2   = (const float*)d_in[6];
    const float* root = (const float*)d_in[7];
    const float* bias = (const float*)d_in[8];

    const int* src = ei;
    const int* dst = ei + NE;

    float* h = (float*)d_out;   // h0, h2, h4 live here (final lands in d_out)

    // workspace layout (d_ws is 8B+ aligned)
    uint2* es     = (uint2*)d_ws;              // NE * 8 B
    int*   bcnt   = (int*)(es + NE);           // NBK      } zeroed together
    int*   deg    = bcnt + NBK;                // NN       }
    float* agg    = (float*)(deg + NN);        // NN       }
    int*   base   = (int*)(agg + NN);          // NBK+1
    int*   cursor = base + (NBK + 1);          // NBK
    float* invdeg = (float*)(cursor + NBK);    // NN
    float* hB     = invdeg + NN;               // NN  (h1, h3)

    const int BLK = 256;
    const int gN = (NN + BLK - 1) / BLK;
    const int gR = NBK * RK;   // 1176

    hipMemsetAsync(bcnt, 0, (size_t)(NBK + NN + NN) * 4, stream);

    bucket_count<<<CPB, BLK, 0, stream>>>(dst, bcnt);
    bucket_scan<<<1, 256, 0, stream>>>(bcnt, base, cursor);
    h_init<<<gN, BLK, 0, stream>>>(x, h);
    place_kernel<<<CPB, BLK, 0, stream>>>(ea, src, dst, w1, b1, w2, b2, cursor, es);

    // round 1 (+deg) : h(d_out) -> hB
    round1_deg<<<gR, BLK, 0, stream>>>(base, es, h, agg, deg);
    update1<<<gN, BLK, 0, stream>>>(deg, invdeg, agg, h, hB, root, bias);
    // round 2 : hB -> h
    round_kernel<<<gR, BLK, 0, stream>>>(base, es, hB, agg);
    update_kernel<<<gN, BLK, 0, stream>>>(invdeg, agg, hB, h, root, bias);
    // round 3 : h -> hB
    round_kernel<<<gR, BLK, 0, stream>>>(base, es, h, agg);
    update_kernel<<<gN, BLK, 0, stream>>>(invdeg, agg, h, hB, root, bias);
    // round 4 : hB -> h (final in d_out)
    round_kernel<<<gR, BLK, 0, stream>>>(base, es, hB, agg);
    update_kernel<<<gN, BLK, 0, stream>>>(invdeg, agg, hB, h, root, bias);
}